// Round 5
// baseline (221.771 us; speedup 1.0000x reference)
//
#include <hip/hip_runtime.h>
#include <stdint.h>

typedef _Float16 f16x8 __attribute__((ext_vector_type(8)));

#define RBITS 10
#define RSZ   1024        // nodes per bucket
#define G     512         // partition blocks for count/scatter
#define MAXB  128         // max buckets (N <= 131072; also s fits 17 bits)

// ---------------- per-node: emb gather/copy, cars1, A/B (f16) ----------------
// Wa/Wb (folded W2e@W3) recomputed per block in LDS (replaces prep kernel).
__global__ __launch_bounds__(256) void node_kernel(
    const int*   __restrict__ features,
    const float* __restrict__ cars,
    const float* __restrict__ entered,
    const float* __restrict__ free_,
    const float* __restrict__ embed_table,
    const float* __restrict__ W2n,   // 33
    const float* __restrict__ b2n,   // 1
    const float* __restrict__ W2e,   // 64x32
    const float* __restrict__ W3,    // 35x8
    float* __restrict__ emb_out,     // N x 32
    float* __restrict__ cars1,       // N
    f16x8* __restrict__ Ah,          // N
    f16x8* __restrict__ Bh,          // N
    float2* __restrict__ sfree,      // N
    int N)
{
    __shared__ float Wa[256], Wb[256];
    {
        int t = threadIdx.x, k = t >> 3, j = t & 7;   // t == k*8+j
        float a = 0.f, b = 0.f;
        #pragma unroll
        for (int m = 0; m < 32; ++m) {
            float w3 = W3[m * 8 + j];
            a += W2e[k * 32 + m]        * w3;
            b += W2e[(32 + k) * 32 + m] * w3;
        }
        Wa[t] = a;
        Wb[t] = b;
    }
    __syncthreads();

    int i = blockIdx.x * blockDim.x + threadIdx.x;
    if (i >= N) return;
    int f = features[i];
    const float4* erow = (const float4*)(embed_table + (size_t)f * 32);
    float4* orow = (float4*)(emb_out + (size_t)i * 32);
    float e[32];
    #pragma unroll
    for (int q = 0; q < 8; ++q) {
        float4 v = erow[q];
        orow[q] = v;
        e[4*q+0] = v.x; e[4*q+1] = v.y; e[4*q+2] = v.z; e[4*q+3] = v.w;
    }
    float parked = b2n[0];
    #pragma unroll
    for (int k = 0; k < 32; ++k) parked += e[k] * W2n[k];
    float c = cars[i];
    parked += c * W2n[32];
    float c1 = fmaxf(fmaxf(parked, 0.f) + c, 0.f);
    cars1[i] = c1;
    sfree[i] = make_float2((float)f, free_[i]);   // features < 2^24: exact in f32

    float ent = entered[i];
    float a8[8], b8[8];
    #pragma unroll
    for (int j = 0; j < 8; ++j) {
        a8[j] = c1 * W3[32*8 + j] + ent * W3[34*8 + j];
        b8[j] = c1 * W3[33*8 + j];
    }
    #pragma unroll
    for (int k = 0; k < 32; ++k) {
        float x = e[k];
        #pragma unroll
        for (int j = 0; j < 8; ++j) {
            a8[j] += x * Wa[k*8 + j];
            b8[j] += x * Wb[k*8 + j];
        }
    }
    f16x8 av, bv;
    #pragma unroll
    for (int j = 0; j < 8; ++j) { av[j] = (_Float16)a8[j]; bv[j] = (_Float16)b8[j]; }
    Ah[i] = av;
    Bh[i] = bv;
}

// ---------------- count: per-(bucket,block) histograms of src & dst ----------
__global__ __launch_bounds__(256) void count_kernel(
    const int* __restrict__ src, const int* __restrict__ dst,
    uint32_t* __restrict__ cntS, uint32_t* __restrict__ cntD, int E, int B)
{
    __shared__ uint32_t cS[MAXB], cD[MAXB];
    for (int i = threadIdx.x; i < MAXB; i += 256) { cS[i] = 0; cD[i] = 0; }
    __syncthreads();
    int per = (E + G - 1) / G;
    int lo = blockIdx.x * per, hi = min(E, lo + per);
    for (int i = lo + threadIdx.x; i < hi; i += 256) {
        atomicAdd(&cS[src[i] >> RBITS], 1u);
        atomicAdd(&cD[dst[i] >> RBITS], 1u);
    }
    __syncthreads();
    for (int i = threadIdx.x; i < B; i += 256) {
        cntS[(size_t)i * G + blockIdx.x] = cS[i];
        cntD[(size_t)i * G + blockIdx.x] = cD[i];
    }
}

// ---------------- scan: in-place exclusive prefix sum (block 0: S, 1: D) -----
__global__ __launch_bounds__(1024) void scan_kernel(
    uint32_t* __restrict__ cntS, uint32_t* __restrict__ cntD, int L)
{
    uint32_t* a = blockIdx.x ? cntD : cntS;
    __shared__ uint32_t part[1024];
    int t = threadIdx.x;
    int C = (L + 1023) / 1024;
    int lo = t * C, hi = min(L, lo + C);
    uint32_t s = 0;
    for (int i = lo; i < hi; ++i) s += a[i];
    part[t] = s;
    __syncthreads();
    for (int d = 1; d < 1024; d <<= 1) {     // Hillis-Steele inclusive
        uint32_t v = (t >= d) ? part[t - d] : 0;
        __syncthreads();
        part[t] += v;
        __syncthreads();
    }
    uint32_t run = (t ? part[t - 1] : 0);
    for (int i = lo; i < hi; ++i) { uint32_t v = a[i]; a[i] = run; run += v; }
}

// -------- scatter: edge math (logit->exp) + partition by src and by dst ------
__global__ __launch_bounds__(256) void scatter_kernel(
    const int* __restrict__ src, const int* __restrict__ dst,
    const float2* __restrict__ sfree,
    const f16x8* __restrict__ Ah, const f16x8* __restrict__ Bh,
    const float* __restrict__ b2e, const float* __restrict__ W3,
    const float* __restrict__ b3,  const float* __restrict__ W4,
    const float* __restrict__ b4,
    const uint32_t* __restrict__ scanS, const uint32_t* __restrict__ scanD,
    uint32_t* __restrict__ payloadS, uint32_t* __restrict__ metaD,
    _Float16* __restrict__ exD, int E, int B)
{
    __shared__ uint32_t curS[MAXB], curD[MAXB];
    __shared__ float b3p[8];
    int t = threadIdx.x, g = blockIdx.x;
    for (int i = t; i < B; i += 256) {
        curS[i] = scanS[(size_t)i * G + g];
        curD[i] = scanD[(size_t)i * G + g];
    }
    if (t < 8) {           // fold b2e@W3 into b3
        float s = b3[t];
        #pragma unroll
        for (int m = 0; m < 32; ++m) s += b2e[m] * W3[m * 8 + t];
        b3p[t] = s;
    }
    __syncthreads();
    float w4[8]; float bias4 = b4[0];
    #pragma unroll
    for (int j = 0; j < 8; ++j) w4[j] = W4[j];

    int per = (E + G - 1) / G;
    int lo = g * per, hi = min(E, lo + per);
    for (int i = lo + t; i < hi; i += 256) {
        int s = src[i], d = dst[i];
        f16x8 av = Ah[s], bv = Bh[d];
        float2 fs = sfree[s];
        float  fd = sfree[d].x;
        float out = bias4;
        #pragma unroll
        for (int j = 0; j < 8; ++j)
            out += fmaxf((float)av[j] + (float)bv[j] + b3p[j], 0.f) * w4[j];
        bool self = (fs.x == fd);
        float enabled = ((self ? 1.f : 0.f) != fs.y) ? 1.f : 0.f;
        float l = fmaxf(out, 0.f) * enabled;
        float ex = __expf(l);                 // l in [0,~6]: no overflow
        unsigned short exh = __builtin_bit_cast(unsigned short, (_Float16)ex);
        uint32_t pS = atomicAdd(&curS[s >> RBITS], 1u);
        payloadS[pS] = (uint32_t)(s & (RSZ - 1)) | ((uint32_t)exh << 16);
        uint32_t pD = atomicAdd(&curD[d >> RBITS], 1u);
        metaD[pD] = (uint32_t)s | ((uint32_t)(d & (RSZ - 1)) << 17)
                  | (self ? 0x80000000u : 0u);
        exD[pD] = (_Float16)ex;
    }
}

// ---------------- bucketS: ssum via LDS, emit ratio = cars1/ssum -------------
__global__ __launch_bounds__(256) void bucketS_kernel(
    const uint32_t* __restrict__ scanS, const uint32_t* __restrict__ payloadS,
    const float* __restrict__ cars1, float* __restrict__ ratio,
    int N, int B, int E)
{
    __shared__ float acc[RSZ];
    int b = blockIdx.x;
    for (int i = threadIdx.x; i < RSZ; i += 256) acc[i] = 0.f;
    __syncthreads();
    uint32_t beg = scanS[(size_t)b * G];
    uint32_t end = (b == B - 1) ? (uint32_t)E : scanS[(size_t)(b + 1) * G];
    for (uint32_t i = beg + threadIdx.x; i < end; i += 256) {
        uint32_t p = payloadS[i];
        float v = (float)__builtin_bit_cast(_Float16, (unsigned short)(p >> 16));
        atomicAdd(&acc[p & (RSZ - 1)], v);         // ds_add_f32
    }
    __syncthreads();
    int base = b << RBITS;
    for (int i = threadIdx.x; i < RSZ; i += 256) {
        int node = base + i;
        if (node < N) {
            float s = acc[i];
            ratio[node] = cars1[node] / (s > 0.f ? s : 1.f);  // unused if deg 0
        }
    }
}

// ------- bucketD: cars/delta via LDS, write cars_out & entered_out -----------
__global__ __launch_bounds__(256) void bucketD_kernel(
    const uint32_t* __restrict__ scanD, const uint32_t* __restrict__ metaD,
    const _Float16* __restrict__ exD, const float* __restrict__ ratio,
    float* __restrict__ cars_out, float* __restrict__ entered_out,
    int N, int B, int E)
{
    __shared__ float accC[RSZ], accX[RSZ];
    int b = blockIdx.x;
    for (int i = threadIdx.x; i < RSZ; i += 256) { accC[i] = 0.f; accX[i] = 0.f; }
    __syncthreads();
    uint32_t beg = scanD[(size_t)b * G];
    uint32_t end = (b == B - 1) ? (uint32_t)E : scanD[(size_t)(b + 1) * G];
    for (uint32_t i = beg + threadIdx.x; i < end; i += 256) {
        uint32_t m = metaD[i];
        float ex = (float)exD[i];
        int s  = m & 0x1FFFF;
        int ld = (m >> 17) & (RSZ - 1);
        float c = ratio[s] * ex;
        atomicAdd(&accC[ld], c);
        if (m & 0x80000000u) atomicAdd(&accX[ld], c);   // selfloop
    }
    __syncthreads();
    int base = b << RBITS;
    for (int i = threadIdx.x; i < RSZ; i += 256) {
        int node = base + i;
        if (node < N) {
            float cs = accC[i];
            cars_out[node]    = cs;
            entered_out[node] = cs - accX[i];
        }
    }
}

extern "C" void kernel_launch(void* const* d_in, const int* in_sizes, int n_in,
                              void* d_out, int out_size, void* d_ws, size_t ws_size,
                              hipStream_t stream)
{
    const int N = in_sizes[0];     // 100000
    const int E = in_sizes[4];     // 1600000
    const int B = (N + RSZ - 1) / RSZ;     // 98 buckets
    const int L = B * G;

    const int*   features    = (const int*)  d_in[0];
    const float* cars        = (const float*)d_in[1];
    const float* entered     = (const float*)d_in[2];
    const float* free_       = (const float*)d_in[3];
    const int*   src         = (const int*)  d_in[4];
    const int*   dst         = (const int*)  d_in[5];
    const float* embed_table = (const float*)d_in[6];
    const float* W2n         = (const float*)d_in[7];
    const float* b2n         = (const float*)d_in[8];
    const float* W2e         = (const float*)d_in[9];
    const float* b2e         = (const float*)d_in[10];
    const float* W3          = (const float*)d_in[11];
    const float* b3          = (const float*)d_in[12];
    const float* W4          = (const float*)d_in[13];
    const float* b4          = (const float*)d_in[14];

    float* out         = (float*)d_out;
    float* cars_out    = out;                       // N
    float* emb_out     = out + N;                   // N*32
    float* entered_out = out + (size_t)N * 33;      // N

    // workspace layout (float offsets)
    float*    ws       = (float*)d_ws;
    float*    cars1    = ws;                              // N
    float*    ratio    = ws + N;                          // N
    float2*   sfree    = (float2*)(ws + (size_t)2 * N);   // N float2
    f16x8*    Ah       = (f16x8*)(ws + (size_t)4 * N);    // N*16B (16B aligned)
    f16x8*    Bh       = (f16x8*)(ws + (size_t)8 * N);    // N*16B
    uint32_t* cntS     = (uint32_t*)(ws + (size_t)12 * N);// L
    uint32_t* cntD     = cntS + L;                        // L
    uint32_t* payloadS = cntD + L;                        // E
    uint32_t* metaD    = payloadS + E;                    // E
    _Float16* exD      = (_Float16*)(metaD + E);          // E halves

    node_kernel<<<(N + 255) / 256, 256, 0, stream>>>(
        features, cars, entered, free_, embed_table, W2n, b2n, W2e, W3,
        emb_out, cars1, Ah, Bh, sfree, N);
    count_kernel<<<G, 256, 0, stream>>>(src, dst, cntS, cntD, E, B);
    scan_kernel<<<2, 1024, 0, stream>>>(cntS, cntD, L);
    scatter_kernel<<<G, 256, 0, stream>>>(
        src, dst, sfree, Ah, Bh, b2e, W3, b3, W4, b4,
        cntS, cntD, payloadS, metaD, exD, E, B);
    bucketS_kernel<<<B, 256, 0, stream>>>(cntS, payloadS, cars1, ratio, N, B, E);
    bucketD_kernel<<<B, 256, 0, stream>>>(
        cntS + L /*==cntD*/, metaD, exD, ratio, cars_out, entered_out, N, B, E);
}

// Round 6
// 125.949 us; speedup vs baseline: 1.7608x; 1.7608x over previous
//
#include <hip/hip_runtime.h>
#include <stdint.h>

typedef _Float16 f16x8 __attribute__((ext_vector_type(8)));

#define RBITS 9
#define RSZ   512         // nodes per bucket
#define G     512         // partition blocks for count/scatter
#define MAXB  256         // max buckets (N <= 131072; s fits 17 bits)

// ---------------- per-node: emb gather/copy, cars1, A/B (f16) ----------------
// Wa/Wb (folded W2e@W3) recomputed per block in LDS.
__global__ __launch_bounds__(256) void node_kernel(
    const int*   __restrict__ features,
    const float* __restrict__ cars,
    const float* __restrict__ entered,
    const float* __restrict__ free_,
    const float* __restrict__ embed_table,
    const float* __restrict__ W2n,   // 33
    const float* __restrict__ b2n,   // 1
    const float* __restrict__ W2e,   // 64x32
    const float* __restrict__ W3,    // 35x8
    float* __restrict__ emb_out,     // N x 32
    float* __restrict__ cars1,       // N
    f16x8* __restrict__ Ah,          // N
    f16x8* __restrict__ Bh,          // N
    float2* __restrict__ sfree,      // N
    int N)
{
    __shared__ float Wa[256], Wb[256];
    {
        int t = threadIdx.x, k = t >> 3, j = t & 7;   // t == k*8+j
        float a = 0.f, b = 0.f;
        #pragma unroll
        for (int m = 0; m < 32; ++m) {
            float w3 = W3[m * 8 + j];
            a += W2e[k * 32 + m]        * w3;
            b += W2e[(32 + k) * 32 + m] * w3;
        }
        Wa[t] = a;
        Wb[t] = b;
    }
    __syncthreads();

    int i = blockIdx.x * blockDim.x + threadIdx.x;
    if (i >= N) return;
    int f = features[i];
    const float4* erow = (const float4*)(embed_table + (size_t)f * 32);
    float4* orow = (float4*)(emb_out + (size_t)i * 32);
    float e[32];
    #pragma unroll
    for (int q = 0; q < 8; ++q) {
        float4 v = erow[q];
        orow[q] = v;
        e[4*q+0] = v.x; e[4*q+1] = v.y; e[4*q+2] = v.z; e[4*q+3] = v.w;
    }
    float parked = b2n[0];
    #pragma unroll
    for (int k = 0; k < 32; ++k) parked += e[k] * W2n[k];
    float c = cars[i];
    parked += c * W2n[32];
    float c1 = fmaxf(fmaxf(parked, 0.f) + c, 0.f);
    cars1[i] = c1;
    sfree[i] = make_float2((float)f, free_[i]);   // features < 2^24: exact in f32

    float ent = entered[i];
    float a8[8], b8[8];
    #pragma unroll
    for (int j = 0; j < 8; ++j) {
        a8[j] = c1 * W3[32*8 + j] + ent * W3[34*8 + j];
        b8[j] = c1 * W3[33*8 + j];
    }
    #pragma unroll
    for (int k = 0; k < 32; ++k) {
        float x = e[k];
        #pragma unroll
        for (int j = 0; j < 8; ++j) {
            a8[j] += x * Wa[k*8 + j];
            b8[j] += x * Wb[k*8 + j];
        }
    }
    f16x8 av, bv;
    #pragma unroll
    for (int j = 0; j < 8; ++j) { av[j] = (_Float16)a8[j]; bv[j] = (_Float16)b8[j]; }
    Ah[i] = av;
    Bh[i] = bv;
}

// ---------------- count: per-(bucket,block) histograms of src & dst ----------
__global__ __launch_bounds__(256) void count_kernel(
    const int* __restrict__ src, const int* __restrict__ dst,
    uint32_t* __restrict__ cntS, uint32_t* __restrict__ cntD, int E, int B)
{
    __shared__ uint32_t cS[MAXB], cD[MAXB];
    for (int i = threadIdx.x; i < MAXB; i += 256) { cS[i] = 0; cD[i] = 0; }
    __syncthreads();
    int per = (E + G - 1) / G;
    int lo = blockIdx.x * per, hi = min(E, lo + per);
    for (int i = lo + threadIdx.x; i < hi; i += 256) {
        atomicAdd(&cS[src[i] >> RBITS], 1u);
        atomicAdd(&cD[dst[i] >> RBITS], 1u);
    }
    __syncthreads();
    for (int i = threadIdx.x; i < B; i += 256) {
        cntS[(size_t)i * G + blockIdx.x] = cS[i];
        cntD[(size_t)i * G + blockIdx.x] = cD[i];
    }
}

// -------- scanA: per-bucket exclusive scan over G blocks (1 block/bucket) ----
__global__ __launch_bounds__(512) void scanA_kernel(
    uint32_t* __restrict__ cntS, uint32_t* __restrict__ cntD,
    uint32_t* __restrict__ totS, uint32_t* __restrict__ totD, int B)
{
    __shared__ uint32_t sh[G];
    int arr = (int)(blockIdx.x >= (unsigned)B);
    int b = blockIdx.x - (arr ? B : 0);
    uint32_t* a   = arr ? cntD : cntS;
    uint32_t* tot = arr ? totD : totS;
    int t = threadIdx.x;
    uint32_t v = a[(size_t)b * G + t];
    sh[t] = v;
    __syncthreads();
    for (int d = 1; d < G; d <<= 1) {        // Hillis-Steele inclusive
        uint32_t u = (t >= d) ? sh[t - d] : 0;
        __syncthreads();
        sh[t] += u;
        __syncthreads();
    }
    a[(size_t)b * G + t] = sh[t] - v;        // exclusive
    if (t == G - 1) tot[b] = sh[t];
}

// -------- scanB: exclusive scan of bucket totals (1 block) -------------------
__global__ __launch_bounds__(256) void scanB_kernel(
    const uint32_t* __restrict__ totS, const uint32_t* __restrict__ totD,
    uint32_t* __restrict__ baseS, uint32_t* __restrict__ baseD, int B)
{
    __shared__ uint32_t sh[256];
    int t = threadIdx.x;
    uint32_t v = (t < B) ? totS[t] : 0;
    sh[t] = v; __syncthreads();
    for (int d = 1; d < 256; d <<= 1) {
        uint32_t u = (t >= d) ? sh[t - d] : 0;
        __syncthreads(); sh[t] += u; __syncthreads();
    }
    if (t < B) baseS[t] = sh[t] - v;
    __syncthreads();
    uint32_t v2 = (t < B) ? totD[t] : 0;
    sh[t] = v2; __syncthreads();
    for (int d = 1; d < 256; d <<= 1) {
        uint32_t u = (t >= d) ? sh[t - d] : 0;
        __syncthreads(); sh[t] += u; __syncthreads();
    }
    if (t < B) baseD[t] = sh[t] - v2;
}

// -------- scatter: edge math (logit->exp) + partition by src and by dst ------
__global__ __launch_bounds__(256) void scatter_kernel(
    const int* __restrict__ src, const int* __restrict__ dst,
    const float2* __restrict__ sfree,
    const f16x8* __restrict__ Ah, const f16x8* __restrict__ Bh,
    const float* __restrict__ b2e, const float* __restrict__ W3,
    const float* __restrict__ b3,  const float* __restrict__ W4,
    const float* __restrict__ b4,
    const uint32_t* __restrict__ cntS, const uint32_t* __restrict__ cntD,
    const uint32_t* __restrict__ baseS, const uint32_t* __restrict__ baseD,
    uint32_t* __restrict__ payloadS, uint64_t* __restrict__ metaEx,
    int E, int B)
{
    __shared__ uint32_t curS[MAXB], curD[MAXB];
    __shared__ float b3p[8];
    int t = threadIdx.x, g = blockIdx.x;
    for (int i = t; i < B; i += 256) {
        curS[i] = baseS[i] + cntS[(size_t)i * G + g];
        curD[i] = baseD[i] + cntD[(size_t)i * G + g];
    }
    if (t < 8) {           // fold b2e@W3 into b3
        float s = b3[t];
        #pragma unroll
        for (int m = 0; m < 32; ++m) s += b2e[m] * W3[m * 8 + t];
        b3p[t] = s;
    }
    __syncthreads();
    float w4[8]; float bias4 = b4[0];
    #pragma unroll
    for (int j = 0; j < 8; ++j) w4[j] = W4[j];

    int per = (E + G - 1) / G;
    int lo = g * per, hi = min(E, lo + per);
    for (int i = lo + t; i < hi; i += 256) {
        int s = src[i], d = dst[i];
        f16x8 av = Ah[s], bv = Bh[d];
        float2 fs = sfree[s];
        float  fd = sfree[d].x;
        float out = bias4;
        #pragma unroll
        for (int j = 0; j < 8; ++j)
            out += fmaxf((float)av[j] + (float)bv[j] + b3p[j], 0.f) * w4[j];
        bool self = (fs.x == fd);
        float enabled = ((self ? 1.f : 0.f) != fs.y) ? 1.f : 0.f;
        float l = fmaxf(out, 0.f) * enabled;
        float ex = __expf(l);                 // l in [0,~6]: no overflow
        uint32_t exh = (uint32_t)__builtin_bit_cast(unsigned short, (_Float16)ex);
        uint32_t pS = atomicAdd(&curS[s >> RBITS], 1u);
        payloadS[pS] = (uint32_t)(s & (RSZ - 1)) | (exh << 16);
        uint32_t pD = atomicAdd(&curD[d >> RBITS], 1u);
        uint32_t meta = (uint32_t)s | ((uint32_t)(d & (RSZ - 1)) << 17)
                      | (self ? 0x80000000u : 0u);
        metaEx[pD] = (uint64_t)meta | ((uint64_t)exh << 32);
    }
}

// ---------------- bucketS: ssum via LDS, emit ratio = cars1/ssum -------------
__global__ __launch_bounds__(256) void bucketS_kernel(
    const uint32_t* __restrict__ baseS, const uint32_t* __restrict__ payloadS,
    const float* __restrict__ cars1, float* __restrict__ ratio,
    int N, int B, int E)
{
    __shared__ float acc[RSZ];
    int b = blockIdx.x;
    for (int i = threadIdx.x; i < RSZ; i += 256) acc[i] = 0.f;
    __syncthreads();
    uint32_t beg = baseS[b];
    uint32_t end = (b == B - 1) ? (uint32_t)E : baseS[b + 1];
    for (uint32_t i = beg + threadIdx.x; i < end; i += 256) {
        uint32_t p = payloadS[i];
        float v = (float)__builtin_bit_cast(_Float16, (unsigned short)(p >> 16));
        atomicAdd(&acc[p & (RSZ - 1)], v);         // ds_add_f32
    }
    __syncthreads();
    int base = b << RBITS;
    for (int i = threadIdx.x; i < RSZ; i += 256) {
        int node = base + i;
        if (node < N) {
            float s = acc[i];
            ratio[node] = cars1[node] / (s > 0.f ? s : 1.f);  // unused if deg 0
        }
    }
}

// ------- bucketD: cars/delta via LDS, write cars_out & entered_out -----------
__global__ __launch_bounds__(256) void bucketD_kernel(
    const uint32_t* __restrict__ baseD, const uint64_t* __restrict__ metaEx,
    const float* __restrict__ ratio,
    float* __restrict__ cars_out, float* __restrict__ entered_out,
    int N, int B, int E)
{
    __shared__ float accC[RSZ], accX[RSZ];
    int b = blockIdx.x;
    for (int i = threadIdx.x; i < RSZ; i += 256) { accC[i] = 0.f; accX[i] = 0.f; }
    __syncthreads();
    uint32_t beg = baseD[b];
    uint32_t end = (b == B - 1) ? (uint32_t)E : baseD[b + 1];
    for (uint32_t i = beg + threadIdx.x; i < end; i += 256) {
        uint64_t me = metaEx[i];
        uint32_t m = (uint32_t)me;
        float ex = (float)__builtin_bit_cast(_Float16, (unsigned short)(me >> 32));
        int s  = m & 0x1FFFF;
        int ld = (m >> 17) & (RSZ - 1);
        float c = ratio[s] * ex;
        atomicAdd(&accC[ld], c);
        if (m & 0x80000000u) atomicAdd(&accX[ld], c);   // selfloop
    }
    __syncthreads();
    int base = b << RBITS;
    for (int i = threadIdx.x; i < RSZ; i += 256) {
        int node = base + i;
        if (node < N) {
            float cs = accC[i];
            cars_out[node]    = cs;
            entered_out[node] = cs - accX[i];
        }
    }
}

extern "C" void kernel_launch(void* const* d_in, const int* in_sizes, int n_in,
                              void* d_out, int out_size, void* d_ws, size_t ws_size,
                              hipStream_t stream)
{
    const int N = in_sizes[0];     // 100000
    const int E = in_sizes[4];     // 1600000
    const int B = (N + RSZ - 1) / RSZ;     // 196 buckets
    const int L = B * G;

    const int*   features    = (const int*)  d_in[0];
    const float* cars        = (const float*)d_in[1];
    const float* entered     = (const float*)d_in[2];
    const float* free_       = (const float*)d_in[3];
    const int*   src         = (const int*)  d_in[4];
    const int*   dst         = (const int*)  d_in[5];
    const float* embed_table = (const float*)d_in[6];
    const float* W2n         = (const float*)d_in[7];
    const float* b2n         = (const float*)d_in[8];
    const float* W2e         = (const float*)d_in[9];
    const float* b2e         = (const float*)d_in[10];
    const float* W3          = (const float*)d_in[11];
    const float* b3          = (const float*)d_in[12];
    const float* W4          = (const float*)d_in[13];
    const float* b4          = (const float*)d_in[14];

    float* out         = (float*)d_out;
    float* cars_out    = out;                       // N
    float* emb_out     = out + N;                   // N*32
    float* entered_out = out + (size_t)N * 33;      // N

    // workspace layout (float offsets; all even -> 8B alignment holds)
    float*    ws       = (float*)d_ws;
    float*    cars1    = ws;                              // N
    float*    ratio    = ws + N;                          // N
    float2*   sfree    = (float2*)(ws + (size_t)2 * N);   // N float2
    f16x8*    Ah       = (f16x8*)(ws + (size_t)4 * N);    // N*16B (16B aligned)
    f16x8*    Bh       = (f16x8*)(ws + (size_t)8 * N);    // N*16B
    uint32_t* cntS     = (uint32_t*)(ws + (size_t)12 * N);// L
    uint32_t* cntD     = cntS + L;                        // L
    uint32_t* totS     = cntD + L;                        // B (<=MAXB)
    uint32_t* totD     = totS + MAXB;                     // B
    uint32_t* baseS    = totD + MAXB;                     // B
    uint32_t* baseD    = baseS + MAXB;                    // B
    uint32_t* payloadS = baseD + MAXB;                    // E
    uint64_t* metaEx   = (uint64_t*)(payloadS + E + (E & 1)); // E u64, 8B-aligned

    node_kernel<<<(N + 255) / 256, 256, 0, stream>>>(
        features, cars, entered, free_, embed_table, W2n, b2n, W2e, W3,
        emb_out, cars1, Ah, Bh, sfree, N);
    count_kernel<<<G, 256, 0, stream>>>(src, dst, cntS, cntD, E, B);
    scanA_kernel<<<2 * B, G, 0, stream>>>(cntS, cntD, totS, totD, B);
    scanB_kernel<<<1, 256, 0, stream>>>(totS, totD, baseS, baseD, B);
    scatter_kernel<<<G, 256, 0, stream>>>(
        src, dst, sfree, Ah, Bh, b2e, W3, b3, W4, b4,
        cntS, cntD, baseS, baseD, payloadS, metaEx, E, B);
    bucketS_kernel<<<B, 256, 0, stream>>>(baseS, payloadS, cars1, ratio, N, B, E);
    bucketD_kernel<<<B, 256, 0, stream>>>(
        baseD, metaEx, ratio, cars_out, entered_out, N, B, E);
}

// Round 7
// 113.770 us; speedup vs baseline: 1.9493x; 1.1071x over previous
//
#include <hip/hip_runtime.h>
#include <stdint.h>

typedef _Float16 f16x8 __attribute__((ext_vector_type(8)));

#define RBITS 9
#define RSZ   512         // nodes per bucket
#define G     512         // partition blocks for count/scatter
#define MAXB  256         // max buckets (N <= 131072; s fits 17 bits)
#define CHMAX 3200        // >= ceil(E/G) = 3125
#define RMAX  13          // >= ceil(CHMAX/256)

// ---------------- per-node: emb gather/copy, cars1, A/B (f16) ----------------
__global__ __launch_bounds__(256) void node_kernel(
    const int*   __restrict__ features,
    const float* __restrict__ cars,
    const float* __restrict__ entered,
    const float* __restrict__ free_,
    const float* __restrict__ embed_table,
    const float* __restrict__ W2n,   // 33
    const float* __restrict__ b2n,   // 1
    const float* __restrict__ W2e,   // 64x32
    const float* __restrict__ W3,    // 35x8
    float* __restrict__ emb_out,     // N x 32
    float* __restrict__ cars1,       // N
    f16x8* __restrict__ Ah,          // N
    f16x8* __restrict__ Bh,          // N
    float2* __restrict__ sfree,      // N
    int N)
{
    __shared__ float Wa[256], Wb[256];
    {
        int t = threadIdx.x, k = t >> 3, j = t & 7;   // t == k*8+j
        float a = 0.f, b = 0.f;
        #pragma unroll
        for (int m = 0; m < 32; ++m) {
            float w3 = W3[m * 8 + j];
            a += W2e[k * 32 + m]        * w3;
            b += W2e[(32 + k) * 32 + m] * w3;
        }
        Wa[t] = a;
        Wb[t] = b;
    }
    __syncthreads();

    int i = blockIdx.x * blockDim.x + threadIdx.x;
    if (i >= N) return;
    int f = features[i];
    const float4* erow = (const float4*)(embed_table + (size_t)f * 32);
    float4* orow = (float4*)(emb_out + (size_t)i * 32);
    float e[32];
    #pragma unroll
    for (int q = 0; q < 8; ++q) {
        float4 v = erow[q];
        orow[q] = v;
        e[4*q+0] = v.x; e[4*q+1] = v.y; e[4*q+2] = v.z; e[4*q+3] = v.w;
    }
    float parked = b2n[0];
    #pragma unroll
    for (int k = 0; k < 32; ++k) parked += e[k] * W2n[k];
    float c = cars[i];
    parked += c * W2n[32];
    float c1 = fmaxf(fmaxf(parked, 0.f) + c, 0.f);
    cars1[i] = c1;
    sfree[i] = make_float2((float)f, free_[i]);   // features < 2^24: exact in f32

    float ent = entered[i];
    float a8[8], b8[8];
    #pragma unroll
    for (int j = 0; j < 8; ++j) {
        a8[j] = c1 * W3[32*8 + j] + ent * W3[34*8 + j];
        b8[j] = c1 * W3[33*8 + j];
    }
    #pragma unroll
    for (int k = 0; k < 32; ++k) {
        float x = e[k];
        #pragma unroll
        for (int j = 0; j < 8; ++j) {
            a8[j] += x * Wa[k*8 + j];
            b8[j] += x * Wb[k*8 + j];
        }
    }
    f16x8 av, bv;
    #pragma unroll
    for (int j = 0; j < 8; ++j) { av[j] = (_Float16)a8[j]; bv[j] = (_Float16)b8[j]; }
    Ah[i] = av;
    Bh[i] = bv;
}

// ---------------- count: per-(bucket,block) histograms of src & dst ----------
__global__ __launch_bounds__(256) void count_kernel(
    const int* __restrict__ src, const int* __restrict__ dst,
    uint32_t* __restrict__ cntS, uint32_t* __restrict__ cntD, int E, int B)
{
    __shared__ uint32_t cS[MAXB], cD[MAXB];
    for (int i = threadIdx.x; i < MAXB; i += 256) { cS[i] = 0; cD[i] = 0; }
    __syncthreads();
    int per = (E + G - 1) / G;
    int lo = blockIdx.x * per, hi = min(E, lo + per);
    for (int i = lo + threadIdx.x; i < hi; i += 256) {
        atomicAdd(&cS[src[i] >> RBITS], 1u);
        atomicAdd(&cD[dst[i] >> RBITS], 1u);
    }
    __syncthreads();
    for (int i = threadIdx.x; i < B; i += 256) {
        cntS[(size_t)i * G + blockIdx.x] = cS[i];
        cntD[(size_t)i * G + blockIdx.x] = cD[i];
    }
}

// -------- scanA: per-bucket exclusive scan over G blocks (1 block/bucket) ----
__global__ __launch_bounds__(512) void scanA_kernel(
    uint32_t* __restrict__ cntS, uint32_t* __restrict__ cntD,
    uint32_t* __restrict__ totS, uint32_t* __restrict__ totD, int B)
{
    __shared__ uint32_t sh[G];
    int arr = (int)(blockIdx.x >= (unsigned)B);
    int b = blockIdx.x - (arr ? B : 0);
    uint32_t* a   = arr ? cntD : cntS;
    uint32_t* tot = arr ? totD : totS;
    int t = threadIdx.x;
    uint32_t v = a[(size_t)b * G + t];
    sh[t] = v;
    __syncthreads();
    for (int d = 1; d < G; d <<= 1) {        // Hillis-Steele inclusive
        uint32_t u = (t >= d) ? sh[t - d] : 0;
        __syncthreads();
        sh[t] += u;
        __syncthreads();
    }
    a[(size_t)b * G + t] = sh[t] - v;        // exclusive
    if (t == G - 1) tot[b] = sh[t];
}

// -------- scanB: exclusive scan of bucket totals (1 block) -------------------
__global__ __launch_bounds__(256) void scanB_kernel(
    const uint32_t* __restrict__ totS, const uint32_t* __restrict__ totD,
    uint32_t* __restrict__ baseS, uint32_t* __restrict__ baseD, int B)
{
    __shared__ uint32_t sh[256];
    int t = threadIdx.x;
    uint32_t v = (t < B) ? totS[t] : 0;
    sh[t] = v; __syncthreads();
    for (int d = 1; d < 256; d <<= 1) {
        uint32_t u = (t >= d) ? sh[t - d] : 0;
        __syncthreads(); sh[t] += u; __syncthreads();
    }
    if (t < B) baseS[t] = sh[t] - v;
    __syncthreads();
    uint32_t v2 = (t < B) ? totD[t] : 0;
    sh[t] = v2; __syncthreads();
    for (int d = 1; d < 256; d <<= 1) {
        uint32_t u = (t >= d) ? sh[t - d] : 0;
        __syncthreads(); sh[t] += u; __syncthreads();
    }
    if (t < B) baseD[t] = sh[t] - v2;
}

// -------- scatterS: edge MLP -> exh linear; bin (s_local, ex) by src bucket --
// LDS-staged: histogram w/ rank, local scan, grouped placement, coalesced flush.
__global__ __launch_bounds__(256) void scatterS_kernel(
    const int* __restrict__ src, const int* __restrict__ dst,
    const float2* __restrict__ sfree,
    const f16x8* __restrict__ Ah, const f16x8* __restrict__ Bh,
    const float* __restrict__ b2e, const float* __restrict__ W3,
    const float* __restrict__ b3,  const float* __restrict__ W4,
    const float* __restrict__ b4,
    const uint32_t* __restrict__ cntS, const uint32_t* __restrict__ baseS,
    uint32_t* __restrict__ payloadS, unsigned short* __restrict__ exh,
    int E, int B)
{
    __shared__ float b3p[8];
    __shared__ uint32_t hcnt[MAXB], hbase[MAXB], cur[MAXB], scanTmp[MAXB];
    __shared__ uint32_t sAddr[CHMAX];
    __shared__ uint32_t sPay[CHMAX];
    int t = threadIdx.x, g = blockIdx.x;
    for (int i = t; i < MAXB; i += 256) {
        hcnt[i] = 0;
        cur[i] = (i < B) ? baseS[i] + cntS[(size_t)i * G + g] : 0;
    }
    if (t < 8) {           // fold b2e@W3 into b3
        float s = b3[t];
        #pragma unroll
        for (int m = 0; m < 32; ++m) s += b2e[m] * W3[m * 8 + t];
        b3p[t] = s;
    }
    __syncthreads();
    float w4[8]; float bias4 = b4[0];
    #pragma unroll
    for (int j = 0; j < 8; ++j) w4[j] = W4[j];

    int per = (E + G - 1) / G;
    int lo = g * per, hi = min(E, lo + per), n = hi - lo;
    int R = (n + 255) >> 8;

    uint32_t meta[RMAX];   // key | rank<<8
    uint32_t pay[RMAX];
    for (int r = 0; r < R; ++r) {
        int idx = r * 256 + t;
        if (idx >= n) continue;
        int i = lo + idx;
        int s = src[i], d = dst[i];
        f16x8 av = Ah[s], bv = Bh[d];
        float2 fs = sfree[s];
        float  fd = sfree[d].x;
        float out = bias4;
        #pragma unroll
        for (int j = 0; j < 8; ++j)
            out += fmaxf((float)av[j] + (float)bv[j] + b3p[j], 0.f) * w4[j];
        bool self = (fs.x == fd);
        float enabled = ((self ? 1.f : 0.f) != fs.y) ? 1.f : 0.f;
        float l = fmaxf(out, 0.f) * enabled;
        float ex = __expf(l);                 // l in [0,~6]: no overflow
        uint32_t exb = (uint32_t)__builtin_bit_cast(unsigned short, (_Float16)ex);
        exh[i] = (unsigned short)(exb | (self ? 0x8000u : 0u)); // sign=selfloop
        uint32_t key = (uint32_t)s >> RBITS;
        uint32_t rank = atomicAdd(&hcnt[key], 1u);
        meta[r] = key | (rank << 8);
        pay[r] = (uint32_t)(s & (RSZ - 1)) | (exb << 16);
    }
    __syncthreads();
    { // exclusive scan of hcnt -> hbase
        uint32_t v = hcnt[t]; scanTmp[t] = v; __syncthreads();
        for (int d = 1; d < 256; d <<= 1) {
            uint32_t u = (t >= d) ? scanTmp[t - d] : 0;
            __syncthreads(); scanTmp[t] += u; __syncthreads();
        }
        hbase[t] = scanTmp[t] - v;
    }
    __syncthreads();
    for (int r = 0; r < R; ++r) {
        int idx = r * 256 + t;
        if (idx >= n) continue;
        uint32_t key = meta[r] & 255u, rank = meta[r] >> 8;
        uint32_t slot = hbase[key] + rank;
        sPay[slot]  = pay[r];
        sAddr[slot] = cur[key] + rank;
    }
    __syncthreads();
    for (int j = t; j < n; j += 256)
        payloadS[sAddr[j]] = sPay[j];
}

// -------- scatterD: read exh linear, bin (s, d_local, self, ex) by dst -------
__global__ __launch_bounds__(256) void scatterD_kernel(
    const int* __restrict__ src, const int* __restrict__ dst,
    const unsigned short* __restrict__ exh,
    const uint32_t* __restrict__ cntD, const uint32_t* __restrict__ baseD,
    uint64_t* __restrict__ metaEx, int E, int B)
{
    __shared__ uint32_t hcnt[MAXB], hbase[MAXB], cur[MAXB], scanTmp[MAXB];
    __shared__ uint32_t sAddr[CHMAX];
    __shared__ uint64_t sPay[CHMAX];
    int t = threadIdx.x, g = blockIdx.x;
    for (int i = t; i < MAXB; i += 256) {
        hcnt[i] = 0;
        cur[i] = (i < B) ? baseD[i] + cntD[(size_t)i * G + g] : 0;
    }
    __syncthreads();
    int per = (E + G - 1) / G;
    int lo = g * per, hi = min(E, lo + per), n = hi - lo;
    int R = (n + 255) >> 8;

    uint32_t meta[RMAX];
    uint32_t payL[RMAX], payH[RMAX];
    for (int r = 0; r < R; ++r) {
        int idx = r * 256 + t;
        if (idx >= n) continue;
        int i = lo + idx;
        int s = src[i], d = dst[i];
        uint32_t ex = exh[i];
        uint32_t self = ex >> 15;
        payL[r] = (uint32_t)s | ((uint32_t)(d & (RSZ - 1)) << 17) | (self << 31);
        payH[r] = ex & 0x7FFFu;
        uint32_t key = (uint32_t)d >> RBITS;
        uint32_t rank = atomicAdd(&hcnt[key], 1u);
        meta[r] = key | (rank << 8);
    }
    __syncthreads();
    {
        uint32_t v = hcnt[t]; scanTmp[t] = v; __syncthreads();
        for (int d = 1; d < 256; d <<= 1) {
            uint32_t u = (t >= d) ? scanTmp[t - d] : 0;
            __syncthreads(); scanTmp[t] += u; __syncthreads();
        }
        hbase[t] = scanTmp[t] - v;
    }
    __syncthreads();
    for (int r = 0; r < R; ++r) {
        int idx = r * 256 + t;
        if (idx >= n) continue;
        uint32_t key = meta[r] & 255u, rank = meta[r] >> 8;
        uint32_t slot = hbase[key] + rank;
        sPay[slot]  = (uint64_t)payL[r] | ((uint64_t)payH[r] << 32);
        sAddr[slot] = cur[key] + rank;
    }
    __syncthreads();
    for (int j = t; j < n; j += 256)
        metaEx[sAddr[j]] = sPay[j];
}

// ---------------- bucketS: ssum via LDS, emit ratio = cars1/ssum -------------
__global__ __launch_bounds__(256) void bucketS_kernel(
    const uint32_t* __restrict__ baseS, const uint32_t* __restrict__ payloadS,
    const float* __restrict__ cars1, float* __restrict__ ratio,
    int N, int B, int E)
{
    __shared__ float acc[RSZ];
    int b = blockIdx.x;
    for (int i = threadIdx.x; i < RSZ; i += 256) acc[i] = 0.f;
    __syncthreads();
    uint32_t beg = baseS[b];
    uint32_t end = (b == B - 1) ? (uint32_t)E : baseS[b + 1];
    for (uint32_t i = beg + threadIdx.x; i < end; i += 256) {
        uint32_t p = payloadS[i];
        float v = (float)__builtin_bit_cast(_Float16, (unsigned short)(p >> 16));
        atomicAdd(&acc[p & (RSZ - 1)], v);         // ds_add_f32
    }
    __syncthreads();
    int base = b << RBITS;
    for (int i = threadIdx.x; i < RSZ; i += 256) {
        int node = base + i;
        if (node < N) {
            float s = acc[i];
            ratio[node] = cars1[node] / (s > 0.f ? s : 1.f);  // unused if deg 0
        }
    }
}

// ------- bucketD: cars/delta via LDS, write cars_out & entered_out -----------
__global__ __launch_bounds__(256) void bucketD_kernel(
    const uint32_t* __restrict__ baseD, const uint64_t* __restrict__ metaEx,
    const float* __restrict__ ratio,
    float* __restrict__ cars_out, float* __restrict__ entered_out,
    int N, int B, int E)
{
    __shared__ float accC[RSZ], accX[RSZ];
    int b = blockIdx.x;
    for (int i = threadIdx.x; i < RSZ; i += 256) { accC[i] = 0.f; accX[i] = 0.f; }
    __syncthreads();
    uint32_t beg = baseD[b];
    uint32_t end = (b == B - 1) ? (uint32_t)E : baseD[b + 1];
    for (uint32_t i = beg + threadIdx.x; i < end; i += 256) {
        uint64_t me = metaEx[i];
        uint32_t m = (uint32_t)me;
        float ex = (float)__builtin_bit_cast(_Float16, (unsigned short)(me >> 32));
        int s  = m & 0x1FFFF;
        int ld = (m >> 17) & (RSZ - 1);
        float c = ratio[s] * ex;
        atomicAdd(&accC[ld], c);
        if (m & 0x80000000u) atomicAdd(&accX[ld], c);   // selfloop
    }
    __syncthreads();
    int base = b << RBITS;
    for (int i = threadIdx.x; i < RSZ; i += 256) {
        int node = base + i;
        if (node < N) {
            float cs = accC[i];
            cars_out[node]    = cs;
            entered_out[node] = cs - accX[i];
        }
    }
}

extern "C" void kernel_launch(void* const* d_in, const int* in_sizes, int n_in,
                              void* d_out, int out_size, void* d_ws, size_t ws_size,
                              hipStream_t stream)
{
    const int N = in_sizes[0];     // 100000
    const int E = in_sizes[4];     // 1600000
    const int B = (N + RSZ - 1) / RSZ;     // 196 buckets
    const int L = B * G;

    const int*   features    = (const int*)  d_in[0];
    const float* cars        = (const float*)d_in[1];
    const float* entered     = (const float*)d_in[2];
    const float* free_       = (const float*)d_in[3];
    const int*   src         = (const int*)  d_in[4];
    const int*   dst         = (const int*)  d_in[5];
    const float* embed_table = (const float*)d_in[6];
    const float* W2n         = (const float*)d_in[7];
    const float* b2n         = (const float*)d_in[8];
    const float* W2e         = (const float*)d_in[9];
    const float* b2e         = (const float*)d_in[10];
    const float* W3          = (const float*)d_in[11];
    const float* b3          = (const float*)d_in[12];
    const float* W4          = (const float*)d_in[13];
    const float* b4          = (const float*)d_in[14];

    float* out         = (float*)d_out;
    float* cars_out    = out;                       // N
    float* emb_out     = out + N;                   // N*32
    float* entered_out = out + (size_t)N * 33;      // N

    // workspace layout (float offsets; all even -> 8B alignment holds)
    float*    ws       = (float*)d_ws;
    float*    cars1    = ws;                              // N
    float*    ratio    = ws + N;                          // N
    float2*   sfree    = (float2*)(ws + (size_t)2 * N);   // N float2
    f16x8*    Ah       = (f16x8*)(ws + (size_t)4 * N);    // N*16B (16B aligned)
    f16x8*    Bh       = (f16x8*)(ws + (size_t)8 * N);    // N*16B
    uint32_t* cntS     = (uint32_t*)(ws + (size_t)12 * N);// L
    uint32_t* cntD     = cntS + L;                        // L
    uint32_t* totS     = cntD + L;                        // B (<=MAXB)
    uint32_t* totD     = totS + MAXB;                     // B
    uint32_t* baseS    = totD + MAXB;                     // B
    uint32_t* baseD    = baseS + MAXB;                    // B
    uint32_t* payloadS = baseD + MAXB;                    // E
    uint64_t* metaEx   = (uint64_t*)(payloadS + E + (E & 1)); // E u64, 8B-aligned
    unsigned short* exh = (unsigned short*)(metaEx + E);  // E u16

    node_kernel<<<(N + 255) / 256, 256, 0, stream>>>(
        features, cars, entered, free_, embed_table, W2n, b2n, W2e, W3,
        emb_out, cars1, Ah, Bh, sfree, N);
    count_kernel<<<G, 256, 0, stream>>>(src, dst, cntS, cntD, E, B);
    scanA_kernel<<<2 * B, G, 0, stream>>>(cntS, cntD, totS, totD, B);
    scanB_kernel<<<1, 256, 0, stream>>>(totS, totD, baseS, baseD, B);
    scatterS_kernel<<<G, 256, 0, stream>>>(
        src, dst, sfree, Ah, Bh, b2e, W3, b3, W4, b4,
        cntS, baseS, payloadS, exh, E, B);
    scatterD_kernel<<<G, 256, 0, stream>>>(
        src, dst, exh, cntD, baseD, metaEx, E, B);
    bucketS_kernel<<<B, 256, 0, stream>>>(baseS, payloadS, cars1, ratio, N, B, E);
    bucketD_kernel<<<B, 256, 0, stream>>>(
        baseD, metaEx, ratio, cars_out, entered_out, N, B, E);
}

// Round 8
// 104.258 us; speedup vs baseline: 2.1271x; 1.0912x over previous
//
#include <hip/hip_runtime.h>
#include <stdint.h>

typedef _Float16 f16x8 __attribute__((ext_vector_type(8)));

#define RBITS 9
#define RSZ   512         // nodes per bucket
#define G     512         // partition blocks for count/scatter
#define MAXB  256         // max buckets (N <= 131072; s fits 17 bits)
#define CHMAX 3200        // >= ceil(E/G) = 3125
#define RMAX  13          // >= ceil(CHMAX/256)

// ---------------- per-node: emb gather/copy, cars1, A/B (f16) ----------------
__global__ __launch_bounds__(256) void node_kernel(
    const int*   __restrict__ features,
    const float* __restrict__ cars,
    const float* __restrict__ entered,
    const float* __restrict__ free_,
    const float* __restrict__ embed_table,
    const float* __restrict__ W2n,   // 33
    const float* __restrict__ b2n,   // 1
    const float* __restrict__ W2e,   // 64x32
    const float* __restrict__ W3,    // 35x8
    float* __restrict__ emb_out,     // N x 32
    float* __restrict__ cars1,       // N
    f16x8* __restrict__ Ah,          // N
    f16x8* __restrict__ Bh,          // N
    float2* __restrict__ sfree,      // N
    int N)
{
    __shared__ float Wa[256], Wb[256];
    {
        int t = threadIdx.x, k = t >> 3, j = t & 7;   // t == k*8+j
        float a = 0.f, b = 0.f;
        #pragma unroll
        for (int m = 0; m < 32; ++m) {
            float w3 = W3[m * 8 + j];
            a += W2e[k * 32 + m]        * w3;
            b += W2e[(32 + k) * 32 + m] * w3;
        }
        Wa[t] = a;
        Wb[t] = b;
    }
    __syncthreads();

    int i = blockIdx.x * blockDim.x + threadIdx.x;
    if (i >= N) return;
    int f = features[i];
    const float4* erow = (const float4*)(embed_table + (size_t)f * 32);
    float4* orow = (float4*)(emb_out + (size_t)i * 32);
    float e[32];
    #pragma unroll
    for (int q = 0; q < 8; ++q) {
        float4 v = erow[q];
        orow[q] = v;
        e[4*q+0] = v.x; e[4*q+1] = v.y; e[4*q+2] = v.z; e[4*q+3] = v.w;
    }
    float parked = b2n[0];
    #pragma unroll
    for (int k = 0; k < 32; ++k) parked += e[k] * W2n[k];
    float c = cars[i];
    parked += c * W2n[32];
    float c1 = fmaxf(fmaxf(parked, 0.f) + c, 0.f);
    cars1[i] = c1;
    sfree[i] = make_float2((float)f, free_[i]);   // features < 2^24: exact in f32

    float ent = entered[i];
    float a8[8], b8[8];
    #pragma unroll
    for (int j = 0; j < 8; ++j) {
        a8[j] = c1 * W3[32*8 + j] + ent * W3[34*8 + j];
        b8[j] = c1 * W3[33*8 + j];
    }
    #pragma unroll
    for (int k = 0; k < 32; ++k) {
        float x = e[k];
        #pragma unroll
        for (int j = 0; j < 8; ++j) {
            a8[j] += x * Wa[k*8 + j];
            b8[j] += x * Wb[k*8 + j];
        }
    }
    f16x8 av, bv;
    #pragma unroll
    for (int j = 0; j < 8; ++j) { av[j] = (_Float16)a8[j]; bv[j] = (_Float16)b8[j]; }
    Ah[i] = av;
    Bh[i] = bv;
}

// ---------------- count: per-(bucket,block) histograms of src & dst ----------
__global__ __launch_bounds__(256) void count_kernel(
    const int* __restrict__ src, const int* __restrict__ dst,
    uint32_t* __restrict__ cntS, uint32_t* __restrict__ cntD, int E, int B)
{
    __shared__ uint32_t cS[MAXB], cD[MAXB];
    for (int i = threadIdx.x; i < MAXB; i += 256) { cS[i] = 0; cD[i] = 0; }
    __syncthreads();
    int per = (E + G - 1) / G;
    int lo = blockIdx.x * per, hi = min(E, lo + per);
    for (int i = lo + threadIdx.x; i < hi; i += 256) {
        atomicAdd(&cS[src[i] >> RBITS], 1u);
        atomicAdd(&cD[dst[i] >> RBITS], 1u);
    }
    __syncthreads();
    for (int i = threadIdx.x; i < B; i += 256) {
        cntS[(size_t)i * G + blockIdx.x] = cS[i];
        cntD[(size_t)i * G + blockIdx.x] = cD[i];
    }
}

// -------- scanA: per-bucket exclusive scan over G blocks (1 block/bucket) ----
__global__ __launch_bounds__(512) void scanA_kernel(
    uint32_t* __restrict__ cntS, uint32_t* __restrict__ cntD,
    uint32_t* __restrict__ totS, uint32_t* __restrict__ totD, int B)
{
    __shared__ uint32_t sh[G];
    int arr = (int)(blockIdx.x >= (unsigned)B);
    int b = blockIdx.x - (arr ? B : 0);
    uint32_t* a   = arr ? cntD : cntS;
    uint32_t* tot = arr ? totD : totS;
    int t = threadIdx.x;
    uint32_t v = a[(size_t)b * G + t];
    sh[t] = v;
    __syncthreads();
    for (int d = 1; d < G; d <<= 1) {        // Hillis-Steele inclusive
        uint32_t u = (t >= d) ? sh[t - d] : 0;
        __syncthreads();
        sh[t] += u;
        __syncthreads();
    }
    a[(size_t)b * G + t] = sh[t] - v;        // exclusive
    if (t == G - 1) tot[b] = sh[t];
}

// -------- scanB: exclusive scan of bucket totals (1 block) -------------------
__global__ __launch_bounds__(256) void scanB_kernel(
    const uint32_t* __restrict__ totS, const uint32_t* __restrict__ totD,
    uint32_t* __restrict__ baseS, uint32_t* __restrict__ baseD, int B)
{
    __shared__ uint32_t sh[256];
    int t = threadIdx.x;
    uint32_t v = (t < B) ? totS[t] : 0;
    sh[t] = v; __syncthreads();
    for (int d = 1; d < 256; d <<= 1) {
        uint32_t u = (t >= d) ? sh[t - d] : 0;
        __syncthreads(); sh[t] += u; __syncthreads();
    }
    if (t < B) baseS[t] = sh[t] - v;
    __syncthreads();
    uint32_t v2 = (t < B) ? totD[t] : 0;
    sh[t] = v2; __syncthreads();
    for (int d = 1; d < 256; d <<= 1) {
        uint32_t u = (t >= d) ? sh[t - d] : 0;
        __syncthreads(); sh[t] += u; __syncthreads();
    }
    if (t < B) baseD[t] = sh[t] - v2;
}

// -------- scatter (fused): edge MLP once; bin by src AND by dst --------------
// Both histograms built in one pass; S then D payloads staged through the
// SAME LDS buffer (union) and flushed coalesced. No exh intermediate.
__global__ __launch_bounds__(256) void scatter_kernel(
    const int* __restrict__ src, const int* __restrict__ dst,
    const float2* __restrict__ sfree,
    const f16x8* __restrict__ Ah, const f16x8* __restrict__ Bh,
    const float* __restrict__ b2e, const float* __restrict__ W3,
    const float* __restrict__ b3,  const float* __restrict__ W4,
    const float* __restrict__ b4,
    const uint32_t* __restrict__ cntS, const uint32_t* __restrict__ cntD,
    const uint32_t* __restrict__ baseS, const uint32_t* __restrict__ baseD,
    uint32_t* __restrict__ payloadS, uint64_t* __restrict__ metaEx,
    int E, int B)
{
    __shared__ float b3p[8];
    __shared__ uint32_t curS[MAXB], curD[MAXB];
    __shared__ uint32_t hcntS[MAXB], hcntD[MAXB];
    __shared__ uint32_t hbaseS[MAXB], hbaseD[MAXB], scanTmp[MAXB];
    __shared__ uint32_t sAddr[CHMAX];
    __shared__ uint64_t sPayU[CHMAX];          // u32 view for S phase
    uint32_t* sPay32 = (uint32_t*)sPayU;

    int t = threadIdx.x, g = blockIdx.x;
    for (int i = t; i < MAXB; i += 256) {
        hcntS[i] = 0; hcntD[i] = 0;
        if (i < B) {
            curS[i] = baseS[i] + cntS[(size_t)i * G + g];
            curD[i] = baseD[i] + cntD[(size_t)i * G + g];
        }
    }
    if (t < 8) {           // fold b2e@W3 into b3
        float s = b3[t];
        #pragma unroll
        for (int m = 0; m < 32; ++m) s += b2e[m] * W3[m * 8 + t];
        b3p[t] = s;
    }
    __syncthreads();
    float w4[8]; float bias4 = b4[0];
    #pragma unroll
    for (int j = 0; j < 8; ++j) w4[j] = W4[j];

    int per = (E + G - 1) / G;
    int lo = g * per, hi = min(E, lo + per), n = hi - lo;
    int R = (n + 255) >> 8;

    // metaS = keyS | rankS<<8               (rank < 3200: bits 8..20)
    // metaD = keyD | rankD<<8 | dloc<<21 | self<<31
    // payS  = s_local(9b) | exb<<16
    uint32_t metaS[RMAX], metaD[RMAX], payS[RMAX];
    for (int r = 0; r < R; ++r) {
        int idx = r * 256 + t;
        if (idx >= n) continue;
        int i = lo + idx;
        int s = src[i], d = dst[i];
        f16x8 av = Ah[s], bv = Bh[d];
        float2 fs = sfree[s];
        float  fd = sfree[d].x;
        float out = bias4;
        #pragma unroll
        for (int j = 0; j < 8; ++j)
            out += fmaxf((float)av[j] + (float)bv[j] + b3p[j], 0.f) * w4[j];
        bool self = (fs.x == fd);
        float enabled = ((self ? 1.f : 0.f) != fs.y) ? 1.f : 0.f;
        float l = fmaxf(out, 0.f) * enabled;
        float ex = __expf(l);                 // l in [0,~6]: no overflow
        uint32_t exb = (uint32_t)__builtin_bit_cast(unsigned short, (_Float16)ex);
        uint32_t keyS = (uint32_t)s >> RBITS;
        uint32_t keyD = (uint32_t)d >> RBITS;
        uint32_t rankS = atomicAdd(&hcntS[keyS], 1u);
        uint32_t rankD = atomicAdd(&hcntD[keyD], 1u);
        metaS[r] = keyS | (rankS << 8);
        metaD[r] = keyD | (rankD << 8) | ((uint32_t)(d & (RSZ - 1)) << 21)
                 | (self ? 0x80000000u : 0u);
        payS[r]  = (uint32_t)(s & (RSZ - 1)) | (exb << 16);
    }
    __syncthreads();
    { // exclusive scans of both histograms
        uint32_t v = hcntS[t]; scanTmp[t] = v; __syncthreads();
        for (int d = 1; d < 256; d <<= 1) {
            uint32_t u = (t >= d) ? scanTmp[t - d] : 0;
            __syncthreads(); scanTmp[t] += u; __syncthreads();
        }
        hbaseS[t] = scanTmp[t] - v;
        __syncthreads();
        uint32_t v2 = hcntD[t]; scanTmp[t] = v2; __syncthreads();
        for (int d = 1; d < 256; d <<= 1) {
            uint32_t u = (t >= d) ? scanTmp[t - d] : 0;
            __syncthreads(); scanTmp[t] += u; __syncthreads();
        }
        hbaseD[t] = scanTmp[t] - v2;
    }
    __syncthreads();

    // ---- S phase: place grouped-by-bucket, flush coalesced ----
    for (int r = 0; r < R; ++r) {
        int idx = r * 256 + t;
        if (idx >= n) continue;
        uint32_t key = metaS[r] & 255u, rank = metaS[r] >> 8;
        uint32_t slot = hbaseS[key] + rank;
        sPay32[slot] = payS[r];
        sAddr[slot]  = curS[key] + rank;
    }
    __syncthreads();
    for (int j = t; j < n; j += 256)
        payloadS[sAddr[j]] = sPay32[j];
    __syncthreads();

    // ---- D phase: reuse the same LDS buffers ----
    for (int r = 0; r < R; ++r) {
        int idx = r * 256 + t;
        if (idx >= n) continue;
        uint32_t m = metaD[r];
        uint32_t key = m & 255u, rank = (m >> 8) & 0x1FFFu;
        uint32_t dloc = (m >> 21) & 0x1FFu, self = m >> 31;
        uint32_t s = ((metaS[r] & 255u) << RBITS) | (payS[r] & (RSZ - 1));
        uint32_t payL = s | (dloc << 17) | (self << 31);
        uint32_t payH = payS[r] >> 16;        // exb (bit15 clear: ex > 0)
        uint32_t slot = hbaseD[key] + rank;
        sPayU[slot] = (uint64_t)payL | ((uint64_t)payH << 32);
        sAddr[slot] = curD[key] + rank;
    }
    __syncthreads();
    for (int j = t; j < n; j += 256)
        metaEx[sAddr[j]] = sPayU[j];
}

// ---------------- bucketS: ssum via LDS, emit ratio = cars1/ssum -------------
__global__ __launch_bounds__(256) void bucketS_kernel(
    const uint32_t* __restrict__ baseS, const uint32_t* __restrict__ payloadS,
    const float* __restrict__ cars1, float* __restrict__ ratio,
    int N, int B, int E)
{
    __shared__ float acc[RSZ];
    int b = blockIdx.x;
    for (int i = threadIdx.x; i < RSZ; i += 256) acc[i] = 0.f;
    __syncthreads();
    uint32_t beg = baseS[b];
    uint32_t end = (b == B - 1) ? (uint32_t)E : baseS[b + 1];
    for (uint32_t i = beg + threadIdx.x; i < end; i += 256) {
        uint32_t p = payloadS[i];
        float v = (float)__builtin_bit_cast(_Float16, (unsigned short)(p >> 16));
        atomicAdd(&acc[p & (RSZ - 1)], v);         // ds_add_f32
    }
    __syncthreads();
    int base = b << RBITS;
    for (int i = threadIdx.x; i < RSZ; i += 256) {
        int node = base + i;
        if (node < N) {
            float s = acc[i];
            ratio[node] = cars1[node] / (s > 0.f ? s : 1.f);  // unused if deg 0
        }
    }
}

// ------- bucketD: cars/delta via LDS, write cars_out & entered_out -----------
__global__ __launch_bounds__(256) void bucketD_kernel(
    const uint32_t* __restrict__ baseD, const uint64_t* __restrict__ metaEx,
    const float* __restrict__ ratio,
    float* __restrict__ cars_out, float* __restrict__ entered_out,
    int N, int B, int E)
{
    __shared__ float accC[RSZ], accX[RSZ];
    int b = blockIdx.x;
    for (int i = threadIdx.x; i < RSZ; i += 256) { accC[i] = 0.f; accX[i] = 0.f; }
    __syncthreads();
    uint32_t beg = baseD[b];
    uint32_t end = (b == B - 1) ? (uint32_t)E : baseD[b + 1];
    for (uint32_t i = beg + threadIdx.x; i < end; i += 256) {
        uint64_t me = metaEx[i];
        uint32_t m = (uint32_t)me;
        float ex = (float)__builtin_bit_cast(_Float16, (unsigned short)(me >> 32));
        int s  = m & 0x1FFFF;
        int ld = (m >> 17) & (RSZ - 1);
        float c = ratio[s] * ex;
        atomicAdd(&accC[ld], c);
        if (m & 0x80000000u) atomicAdd(&accX[ld], c);   // selfloop
    }
    __syncthreads();
    int base = b << RBITS;
    for (int i = threadIdx.x; i < RSZ; i += 256) {
        int node = base + i;
        if (node < N) {
            float cs = accC[i];
            cars_out[node]    = cs;
            entered_out[node] = cs - accX[i];
        }
    }
}

extern "C" void kernel_launch(void* const* d_in, const int* in_sizes, int n_in,
                              void* d_out, int out_size, void* d_ws, size_t ws_size,
                              hipStream_t stream)
{
    const int N = in_sizes[0];     // 100000
    const int E = in_sizes[4];     // 1600000
    const int B = (N + RSZ - 1) / RSZ;     // 196 buckets
    const int L = B * G;

    const int*   features    = (const int*)  d_in[0];
    const float* cars        = (const float*)d_in[1];
    const float* entered     = (const float*)d_in[2];
    const float* free_       = (const float*)d_in[3];
    const int*   src         = (const int*)  d_in[4];
    const int*   dst         = (const int*)  d_in[5];
    const float* embed_table = (const float*)d_in[6];
    const float* W2n         = (const float*)d_in[7];
    const float* b2n         = (const float*)d_in[8];
    const float* W2e         = (const float*)d_in[9];
    const float* b2e         = (const float*)d_in[10];
    const float* W3          = (const float*)d_in[11];
    const float* b3          = (const float*)d_in[12];
    const float* W4          = (const float*)d_in[13];
    const float* b4          = (const float*)d_in[14];

    float* out         = (float*)d_out;
    float* cars_out    = out;                       // N
    float* emb_out     = out + N;                   // N*32
    float* entered_out = out + (size_t)N * 33;      // N

    // workspace layout (float offsets; all even -> 8B alignment holds)
    float*    ws       = (float*)d_ws;
    float*    cars1    = ws;                              // N
    float*    ratio    = ws + N;                          // N
    float2*   sfree    = (float2*)(ws + (size_t)2 * N);   // N float2
    f16x8*    Ah       = (f16x8*)(ws + (size_t)4 * N);    // N*16B (16B aligned)
    f16x8*    Bh       = (f16x8*)(ws + (size_t)8 * N);    // N*16B
    uint32_t* cntS     = (uint32_t*)(ws + (size_t)12 * N);// L
    uint32_t* cntD     = cntS + L;                        // L
    uint32_t* totS     = cntD + L;                        // B (<=MAXB)
    uint32_t* totD     = totS + MAXB;                     // B
    uint32_t* baseS    = totD + MAXB;                     // B
    uint32_t* baseD    = baseS + MAXB;                    // B
    uint32_t* payloadS = baseD + MAXB;                    // E
    uint64_t* metaEx   = (uint64_t*)(payloadS + E + (E & 1)); // E u64, 8B-aligned

    node_kernel<<<(N + 255) / 256, 256, 0, stream>>>(
        features, cars, entered, free_, embed_table, W2n, b2n, W2e, W3,
        emb_out, cars1, Ah, Bh, sfree, N);
    count_kernel<<<G, 256, 0, stream>>>(src, dst, cntS, cntD, E, B);
    scanA_kernel<<<2 * B, G, 0, stream>>>(cntS, cntD, totS, totD, B);
    scanB_kernel<<<1, 256, 0, stream>>>(totS, totD, baseS, baseD, B);
    scatter_kernel<<<G, 256, 0, stream>>>(
        src, dst, sfree, Ah, Bh, b2e, W3, b3, W4, b4,
        cntS, cntD, baseS, baseD, payloadS, metaEx, E, B);
    bucketS_kernel<<<B, 256, 0, stream>>>(baseS, payloadS, cars1, ratio, N, B, E);
    bucketD_kernel<<<B, 256, 0, stream>>>(
        baseD, metaEx, ratio, cars_out, entered_out, N, B, E);
}